// Round 7
// baseline (230.739 us; speedup 1.0000x reference)
//
#include <hip/hip_runtime.h>

typedef short short8 __attribute__((ext_vector_type(8)));
typedef float floatx4 __attribute__((ext_vector_type(4)));
typedef unsigned short u16;
typedef unsigned long long u64;

#define Tn 2048
#define Kdim 1024
// 1/sqrt(64) * log2(e): folded into Q so flash softmax runs in exp2 domain
#define QSCALE 0.18033688011112042f
#define FIXEDMAX 20.0f   // exp2-domain logits are ~+-5; 20 is a safe fixed max

__device__ inline u16 f2bf(float x) {
    union { float f; unsigned u; } c; c.f = x;
    unsigned u = c.u;
    u += 0x7fffu + ((u >> 16) & 1u);   // round-to-nearest-even
    return (u16)(u >> 16);
}
__device__ inline float bf2f(u16 h) {
    union { unsigned u; float f; } c; c.u = ((unsigned)h) << 16;
    return c.f;
}
__device__ inline floatx4 mfma16(short8 a, short8 b, floatx4 c) {
    return __builtin_amdgcn_mfma_f32_16x16x32_bf16(a, b, c, 0, 0, 0);
}
__device__ inline void async16(const void* g, void* l) {
    __builtin_amdgcn_global_load_lds((const __attribute__((address_space(1))) void*)g,
                                     (__attribute__((address_space(3))) void*)l, 16, 0, 0);
}

// ---------------- fused f32 -> bf16 convert (x, Wq, Wk, Wv, Wo) ----------------
__global__ __launch_bounds__(256) void cvt_all_k(
    const float* __restrict__ x, const float* __restrict__ wq, const float* __restrict__ wk,
    const float* __restrict__ wv, const float* __restrict__ wo, u16* __restrict__ dst)
{
    int i = blockIdx.x * 256 + threadIdx.x;   // float4 index
    const float* s; int off;
    if (i < 1048576) { s = x; off = i; }
    else {
        int j = i - 1048576; int seg = j >> 18; off = j & 262143;
        s = (seg == 0) ? wq : (seg == 1) ? wk : (seg == 2) ? wv : wo;
    }
    float4 v = ((const float4*)s)[off];
    u64 pk = (u64)f2bf(v.x) | ((u64)f2bf(v.y) << 16) | ((u64)f2bf(v.z) << 32) | ((u64)f2bf(v.w) << 48);
    ((u64*)dst)[i] = pk;
}

// ---------------- QKV GEMM: C = A(M,K) @ W(N,K)^T + bias, 128M x 64N tile, BK=64 ----------------
__global__ __launch_bounds__(256, 5) void gemm_qkv_k(
    const u16* __restrict__ A,
    const u16* __restrict__ W0, const u16* __restrict__ W1, const u16* __restrict__ W2,
    const float* __restrict__ b0, const float* __restrict__ b1, const float* __restrict__ b2,
    u16* o0, u16* o1, u16* o2,
    const float2* __restrict__ rope)
{
    int z = blockIdx.z;
    const u16* W = (z == 0) ? W0 : (z == 1 ? W1 : W2);
    const float* bias = (z == 0) ? b0 : (z == 1 ? b1 : b2);
    u16* outp = (z == 0) ? o0 : (z == 1 ? o1 : o2);

    __shared__ __align__(16) char lds[24576];   // A [0,16K): 128 rows x 128B; W [16K,24K): 64 rows x 128B
    int tid = threadIdx.x;
    int w = tid >> 6, lane = tid & 63, quad = lane >> 4, l15 = lane & 15;
    int m0 = blockIdx.y * 128, n0 = blockIdx.x * 64;
    int wm = w * 32;

    floatx4 acc[2][4];
    floatx4 vzero = {0.f, 0.f, 0.f, 0.f};
#pragma unroll
    for (int i = 0; i < 2; ++i)
#pragma unroll
        for (int j = 0; j < 4; ++j) acc[i][j] = vzero;

    for (int k0 = 0; k0 < Kdim; k0 += 64) {
#pragma unroll
        for (int j = 0; j < 4; ++j) {
            int f = j * 256 + tid, r = f >> 3, c = (f & 7) ^ (r & 7);
            async16(A + (size_t)(m0 + r) * Kdim + k0 + c * 8, lds + j * 4096 + w * 1024);
        }
#pragma unroll
        for (int j = 0; j < 2; ++j) {
            int f = j * 256 + tid, r = f >> 3, c = (f & 7) ^ (r & 7);
            async16(W + (size_t)(n0 + r) * Kdim + k0 + c * 8, lds + 16384 + j * 4096 + w * 1024);
        }
        __syncthreads();
        short8 af[2][2];
#pragma unroll
        for (int mt = 0; mt < 2; ++mt) {
            int ra = wm + mt * 16 + l15;
            const char* pa = lds + ra * 128;
#pragma unroll
            for (int ks = 0; ks < 2; ++ks)
                af[mt][ks] = *(const short8*)(pa + (((ks * 4 + quad) ^ (ra & 7)) << 4));
        }
#pragma unroll
        for (int ks = 0; ks < 2; ++ks)
#pragma unroll
            for (int nt = 0; nt < 4; ++nt) {
                int rb = nt * 16 + l15;
                short8 bf = *(const short8*)(lds + 16384 + rb * 128 + (((ks * 4 + quad) ^ (rb & 7)) << 4));
                acc[0][nt] = mfma16(af[0][ks], bf, acc[0][nt]);
                acc[1][nt] = mfma16(af[1][ks], bf, acc[1][nt]);
            }
        __syncthreads();
    }

    int mbase = m0 + wm;
    if (z <= 1) {
        float osc = (z == 0) ? QSCALE : 1.0f;
#pragma unroll
        for (int nt = 0; nt < 4; ++nt) {
            int col = n0 + nt * 16 + l15;
            float bv = bias[col];
            int p = (col & 63) >> 1;
#pragma unroll
            for (int mt = 0; mt < 2; ++mt) {
                floatx4 a = acc[mt][nt];
#pragma unroll
                for (int r = 0; r < 4; ++r) {
                    int row = mbase + mt * 16 + quad * 4 + r;
                    float v = a[r] + bv;
                    float ov = __shfl_xor(v, 1, 64);
                    float2 cs = rope[(row & (Tn - 1)) * 32 + p];
                    float res = (cs.x * v + ((lane & 1) ? cs.y * ov : -cs.y * ov)) * osc;
                    float pres = __shfl_xor(res, 1, 64);
                    if (!(lane & 1)) {
                        unsigned pk = (unsigned)f2bf(res) | ((unsigned)f2bf(pres) << 16);
                        *(unsigned*)(outp + (size_t)row * 1024 + col) = pk;
                    }
                }
            }
        }
    } else {
#pragma unroll
        for (int nt = 0; nt < 4; ++nt) {
            int col = n0 + nt * 16 + l15;
            float bv = bias[col];
#pragma unroll
            for (int mt = 0; mt < 2; ++mt) {
                floatx4 a = acc[mt][nt];
                int row0 = mbase + mt * 16 + quad * 4;
                int bb = row0 >> 11, t0 = row0 & (Tn - 1);
                u64 pk = (u64)f2bf(a[0] + bv) | ((u64)f2bf(a[1] + bv) << 16)
                       | ((u64)f2bf(a[2] + bv) << 32) | ((u64)f2bf(a[3] + bv) << 48);
                *(u64*)(outp + (size_t)(bb * 1024 + col) * Tn + t0) = pk;
            }
        }
    }
}

// ---------------- O-projection GEMM: out = Y(M,K) @ Wo(N,K)^T, f32 out, 64x64 tile ----------------
__global__ __launch_bounds__(256, 6) void gemm_o_k(
    const u16* __restrict__ A, const u16* __restrict__ W, float* __restrict__ out)
{
    __shared__ __align__(16) char lds[16384];
    int tid = threadIdx.x;
    int w = tid >> 6, lane = tid & 63, quad = lane >> 4, l15 = lane & 15;
    int m0 = blockIdx.y * 64, n0 = blockIdx.x * 64;
    int wm = (w >> 1) * 32, wn = (w & 1) * 32;

    floatx4 acc[2][2];
    floatx4 vzero = {0.f, 0.f, 0.f, 0.f};
#pragma unroll
    for (int i = 0; i < 2; ++i)
#pragma unroll
        for (int j = 0; j < 2; ++j) acc[i][j] = vzero;

    for (int k0 = 0; k0 < Kdim; k0 += 64) {
#pragma unroll
        for (int j = 0; j < 2; ++j) {
            int f = j * 256 + tid, r = f >> 3, c = (f & 7) ^ (r & 7);
            async16(A + (size_t)(m0 + r) * Kdim + k0 + c * 8, lds + j * 4096 + w * 1024);
            async16(W + (size_t)(n0 + r) * Kdim + k0 + c * 8, lds + 8192 + j * 4096 + w * 1024);
        }
        __syncthreads();
        short8 af[2][2];
#pragma unroll
        for (int mt = 0; mt < 2; ++mt) {
            int ra = wm + mt * 16 + l15;
            const char* pa = lds + ra * 128;
#pragma unroll
            for (int ks = 0; ks < 2; ++ks)
                af[mt][ks] = *(const short8*)(pa + (((ks * 4 + quad) ^ (ra & 7)) << 4));
        }
#pragma unroll
        for (int ks = 0; ks < 2; ++ks)
#pragma unroll
            for (int nt = 0; nt < 2; ++nt) {
                int rb = wn + nt * 16 + l15;
                short8 bf = *(const short8*)(lds + 8192 + rb * 128 + (((ks * 4 + quad) ^ (rb & 7)) << 4));
                acc[0][nt] = mfma16(af[0][ks], bf, acc[0][nt]);
                acc[1][nt] = mfma16(af[1][ks], bf, acc[1][nt]);
            }
        __syncthreads();
    }

#pragma unroll
    for (int nt = 0; nt < 2; ++nt) {
        int col = n0 + wn + nt * 16 + l15;
#pragma unroll
        for (int mt = 0; mt < 2; ++mt) {
            floatx4 a = acc[mt][nt];
#pragma unroll
            for (int r = 0; r < 4; ++r) {
                int row = m0 + wm + mt * 16 + quad * 4 + r;
                out[(size_t)row * 1024 + col] = a[r];
            }
        }
    }
}

// ---------------- Vmean (for degenerate fully-masked rows) ----------------
__global__ __launch_bounds__(64) void vmean_k(const u16* __restrict__ Vt, float* __restrict__ vmean) {
    int row = blockIdx.x;
    int lane = threadIdx.x;
    const u16* p = Vt + (size_t)row * Tn;
    float s = 0.f;
    for (int i = lane * 8; i < Tn; i += 512) {
        short8 v = *(const short8*)(p + i);
#pragma unroll
        for (int j = 0; j < 8; ++j) s += bf2f((u16)v[j]);
    }
#pragma unroll
    for (int off = 1; off < 64; off <<= 1) s += __shfl_xor(s, off, 64);
    if (lane == 0) vmean[row] = s * (1.f / 2048.f);
}

// ---------------- Flash attention v3: barrier-free, per-wave 32-q strips ----------------
// 1024 blocks x 128 threads (2 waves). Wave owns q [qs, qs+31] of one (b,h); K/V frags
// read DIRECTLY from global (L2-resident via XCD clustering) -> no __syncthreads at all.
// Only wave-private LDS for the P C-layout -> A-layout roundtrip (in-order DS pipe).
// Fixed-max exp2 softmax; mask + (-FIXEDMAX) folded into QK accumulator init.
__global__ __launch_bounds__(128) void flash_k(
    const u16* __restrict__ Qb, const u16* __restrict__ Kb, const u16* __restrict__ Vt,
    const int* __restrict__ masks, const float* __restrict__ vmean, u16* __restrict__ Yb)
{
    int bid = blockIdx.x;
    int bh = (bid & 7) * 4 + ((bid >> 3) & 3);   // XCD-clustered: 4 heads per XCD (bid%8)
    int blkq = 31 - (bid >> 5);                  // big q-tiles dispatched first
    int b = bh >> 4, h = bh & 15;
    int tid = threadIdx.x, w = tid >> 6, lane = tid & 63, quad = lane >> 4, l15 = lane & 15;

    __shared__ __align__(16) u16 ldsP[2][16 * 64];   // per-wave P, 16 rows x 128B, swizzled

    int qs = blkq * 64 + w * 32;                 // both waves have the same ktile count
    int ktiles = (qs >> 6) + 1;

    // mask ballots: lane j holds ballot of key-tile j (all 32 prefetched, loads pipeline)
    int mv[32];
#pragma unroll
    for (int j = 0; j < 32; ++j) mv[j] = masks[b * Tn + j * 64 + lane];
    unsigned blo = 0, bhi = 0;
#pragma unroll
    for (int j = 0; j < 32; ++j) {
        u64 mk = __ballot(mv[j] != 0);
        if (lane == j) { blo = (unsigned)mk; bhi = (unsigned)(mk >> 32); }
    }

    short8 qf[2][2];
#pragma unroll
    for (int s2 = 0; s2 < 2; ++s2) {
        const u16* qp = Qb + (size_t)(b * Tn + qs + s2 * 16 + l15) * 1024 + h * 64 + quad * 8;
        qf[s2][0] = *(const short8*)qp;
        qf[s2][1] = *(const short8*)(qp + 32);
    }

    floatx4 o[2][4];
    float lsum[2][4];
#pragma unroll
    for (int s2 = 0; s2 < 2; ++s2)
#pragma unroll
        for (int i = 0; i < 4; ++i) { o[s2][i] = (floatx4){0.f, 0.f, 0.f, 0.f}; lsum[s2][i] = 0.f; }

    // uniform bases advance per tile; lane offsets are loop-invariant
    const u16* ku = Kb + (size_t)b * Tn * 1024 + h * 64;
    const u16* vu = Vt + ((size_t)b * 1024 + h * 64) * Tn;
    int klo = l15 * 1024 + quad * 8;
    int vlo = l15 * Tn + quad * 8;
    int pswz = l15 >> 3, pbyte = (l15 & 7) * 2;

    for (int kt = 0; kt < ktiles; ++kt) {
        short8 kf[4][2], vf[4][2];
#pragma unroll
        for (int f = 0; f < 4; ++f) {
#pragma unroll
            for (int ks = 0; ks < 2; ++ks) {
                kf[f][ks] = *(const short8*)(ku + klo + f * 16 * 1024 + ks * 32);
                vf[f][ks] = *(const short8*)(vu + vlo + f * 16 * Tn + ks * 32);
            }
        }
        ku += 64 * 1024;   // next 64 key rows
        vu += 64;          // next 64 key cols

        unsigned mlo = __shfl(blo, kt, 64), mhi = __shfl(bhi, kt, 64);
        float mi[4];
        mi[0] = ((mlo >> l15) & 1) ? -1.0e10f : -FIXEDMAX;
        mi[1] = ((mlo >> (l15 + 16)) & 1) ? -1.0e10f : -FIXEDMAX;
        mi[2] = ((mhi >> l15) & 1) ? -1.0e10f : -FIXEDMAX;
        mi[3] = ((mhi >> (l15 + 16)) & 1) ? -1.0e10f : -FIXEDMAX;

        floatx4 sA[2][4];
#pragma unroll
        for (int s2 = 0; s2 < 2; ++s2)
#pragma unroll
            for (int f = 0; f < 4; ++f) {
                floatx4 c = (floatx4){mi[f], mi[f], mi[f], mi[f]};
                c = mfma16(qf[s2][0], kf[f][0], c);
                sA[s2][f] = mfma16(qf[s2][1], kf[f][1], c);
            }

        bool diag = (kt == ktiles - 1);
#pragma unroll
        for (int s2 = 0; s2 < 2; ++s2) {
            char* pb = (char*)&ldsP[w][0];
            if (diag) {
#pragma unroll
                for (int r = 0; r < 4; ++r) {
                    int row = quad * 4 + r;
                    int lim = qs + s2 * 16 + row - (kt << 6);
                    float ps = 0.f;
#pragma unroll
                    for (int f = 0; f < 4; ++f) {
                        float v = (f * 16 + l15 > lim) ? -1.0e10f : sA[s2][f][r];
                        float p = __builtin_amdgcn_exp2f(v);
                        ps += p;
                        unsigned u = __float_as_uint(p) + 0x8000u;   // round-half-up bf16
                        *(u16*)(pb + row * 128 + (((2 * f + pswz) ^ (row & 7)) << 4) + pbyte) = (u16)(u >> 16);
                    }
                    lsum[s2][r] += ps;
                }
            } else {
#pragma unroll
                for (int r = 0; r < 4; ++r) {
                    int row = quad * 4 + r;
                    float ps = 0.f;
#pragma unroll
                    for (int f = 0; f < 4; ++f) {
                        float p = __builtin_amdgcn_exp2f(sA[s2][f][r]);
                        ps += p;
                        unsigned u = __float_as_uint(p) + 0x8000u;
                        *(u16*)(pb + row * 128 + (((2 * f + pswz) ^ (row & 7)) << 4) + pbyte) = (u16)(u >> 16);
                    }
                    lsum[s2][r] += ps;
                }
            }
            __asm__ volatile("s_waitcnt lgkmcnt(0)" ::: "memory");   // wave-local P roundtrip
            short8 pf0 = *(const short8*)(pb + l15 * 128 + ((quad ^ (l15 & 7)) << 4));
            short8 pf1 = *(const short8*)(pb + l15 * 128 + (((quad + 4) ^ (l15 & 7)) << 4));
#pragma unroll
            for (int nb = 0; nb < 4; ++nb) {
                o[s2][nb] = mfma16(pf0, vf[nb][0], o[s2][nb]);
                o[s2][nb] = mfma16(pf1, vf[nb][1], o[s2][nb]);
            }
        }
    }

#pragma unroll
    for (int s2 = 0; s2 < 2; ++s2)
#pragma unroll
        for (int r = 0; r < 4; ++r) {
            int qq = qs + s2 * 16 + quad * 4 + r;
            float l = lsum[s2][r];
#pragma unroll
            for (int off = 1; off < 16; off <<= 1) l += __shfl_xor(l, off, 64);
            bool degen = (l == 0.f);   // fully-masked row -> reference attends uniformly to ALL keys
            float linv = 1.0f / l;
#pragma unroll
            for (int nb = 0; nb < 4; ++nb) {
                int d = nb * 16 + l15;
                float val = degen ? vmean[b * 1024 + h * 64 + d] : o[s2][nb][r] * linv;
                float pv = __shfl_xor(val, 1, 64);
                if (!(lane & 1)) {
                    unsigned pk = (unsigned)f2bf(val) | ((unsigned)f2bf(pv) << 16);
                    *(unsigned*)(Yb + (size_t)(b * Tn + qq) * 1024 + h * 64 + d) = pk;
                }
            }
        }
}

extern "C" void kernel_launch(void* const* d_in, const int* in_sizes, int n_in,
                              void* d_out, int out_size, void* d_ws, size_t ws_size,
                              hipStream_t stream) {
    const float* x  = (const float*)d_in[0];
    const int* masks = (const int*)d_in[1];
    const float* Wq = (const float*)d_in[2];
    const float* bq = (const float*)d_in[3];
    const float* Wk = (const float*)d_in[4];
    const float* bk = (const float*)d_in[5];
    const float* Wv = (const float*)d_in[6];
    const float* bv = (const float*)d_in[7];
    const float* Wo = (const float*)d_in[8];
    const float2* rope = (const float2*)d_in[9];
    float* out = (float*)d_out;

    char* ws = (char*)d_ws;
    u16* xb   = (u16*)(ws);
    u16* Wqb  = (u16*)(ws + (8  << 20));
    u16* Wkb  = (u16*)(ws + (10 << 20));
    u16* Wvb  = (u16*)(ws + (12 << 20));
    u16* Wob  = (u16*)(ws + (14 << 20));
    u16* Qb   = (u16*)(ws + (16 << 20));
    u16* Kb2  = (u16*)(ws + (24 << 20));
    u16* Vt   = (u16*)(ws + (32 << 20));
    u16* Yb   = (u16*)(ws + (40 << 20));
    float* vm = (float*)(ws + (48 << 20));

    // fused f32 -> bf16 (x, Wq, Wk, Wv, Wo -> contiguous ws region)
    cvt_all_k<<<8192, 256, 0, stream>>>(x, Wq, Wk, Wv, Wo, xb);

    // fused QKV projection (+bias, rope on Q/K with QSCALE on Q, V transposed)
    gemm_qkv_k<<<dim3(16, 32, 3), 256, 0, stream>>>(xb, Wqb, Wkb, Wvb, bq, bk, bv,
                                                    Qb, Kb2, Vt, rope);
    // mean of V per (b,h,d) for degenerate fully-masked rows
    vmean_k<<<2048, 64, 0, stream>>>(Vt, vm);
    // flash attention (barrier-free, per-wave strips)
    flash_k<<<1024, 128, 0, stream>>>(Qb, Kb2, Vt, masks, vm, Yb);
    // output projection -> f32 d_out
    gemm_o_k<<<dim3(16, 64), 256, 0, stream>>>(Yb, Wob, out);
}

// Round 8
// 208.462 us; speedup vs baseline: 1.1069x; 1.1069x over previous
//
#include <hip/hip_runtime.h>

typedef short short8 __attribute__((ext_vector_type(8)));
typedef float floatx4 __attribute__((ext_vector_type(4)));
typedef unsigned short u16;
typedef unsigned long long u64;

#define Tn 2048
#define Kdim 1024
// 1/sqrt(64) * log2(e): folded into Q so flash softmax runs in exp2 domain
#define QSCALE 0.18033688011112042f
#define FIXEDMAX 20.0f   // exp2-domain logits are ~+-5; 20 is a safe fixed max

__device__ inline u16 f2bf(float x) {
    union { float f; unsigned u; } c; c.f = x;
    unsigned u = c.u;
    u += 0x7fffu + ((u >> 16) & 1u);   // round-to-nearest-even
    return (u16)(u >> 16);
}
__device__ inline float bf2f(u16 h) {
    union { unsigned u; float f; } c; c.u = ((unsigned)h) << 16;
    return c.f;
}
__device__ inline floatx4 mfma16(short8 a, short8 b, floatx4 c) {
    return __builtin_amdgcn_mfma_f32_16x16x32_bf16(a, b, c, 0, 0, 0);
}
__device__ inline void async16(const void* g, void* l) {
    __builtin_amdgcn_global_load_lds((const __attribute__((address_space(1))) void*)g,
                                     (__attribute__((address_space(3))) void*)l, 16, 0, 0);
}

// ---------------- fused f32 -> bf16 convert (x, Wq, Wk, Wv, Wo) ----------------
__global__ __launch_bounds__(256) void cvt_all_k(
    const float* __restrict__ x, const float* __restrict__ wq, const float* __restrict__ wk,
    const float* __restrict__ wv, const float* __restrict__ wo, u16* __restrict__ dst)
{
    int i = blockIdx.x * 256 + threadIdx.x;   // float4 index
    const float* s; int off;
    if (i < 1048576) { s = x; off = i; }
    else {
        int j = i - 1048576; int seg = j >> 18; off = j & 262143;
        s = (seg == 0) ? wq : (seg == 1) ? wk : (seg == 2) ? wv : wo;
    }
    float4 v = ((const float4*)s)[off];
    u64 pk = (u64)f2bf(v.x) | ((u64)f2bf(v.y) << 16) | ((u64)f2bf(v.z) << 32) | ((u64)f2bf(v.w) << 48);
    ((u64*)dst)[i] = pk;
}

// ---------------- QKV GEMM: C = A(M,K) @ W(N,K)^T + bias, 128M x 64N tile, BK=64 ----------------
__global__ __launch_bounds__(256, 5) void gemm_qkv_k(
    const u16* __restrict__ A,
    const u16* __restrict__ W0, const u16* __restrict__ W1, const u16* __restrict__ W2,
    const float* __restrict__ b0, const float* __restrict__ b1, const float* __restrict__ b2,
    u16* o0, u16* o1, u16* o2,
    const float2* __restrict__ rope)
{
    int z = blockIdx.z;
    const u16* W = (z == 0) ? W0 : (z == 1 ? W1 : W2);
    const float* bias = (z == 0) ? b0 : (z == 1 ? b1 : b2);
    u16* outp = (z == 0) ? o0 : (z == 1 ? o1 : o2);

    __shared__ __align__(16) char lds[24576];   // A [0,16K): 128 rows x 128B; W [16K,24K): 64 rows x 128B
    int tid = threadIdx.x;
    int w = tid >> 6, lane = tid & 63, quad = lane >> 4, l15 = lane & 15;
    int m0 = blockIdx.y * 128, n0 = blockIdx.x * 64;
    int wm = w * 32;

    floatx4 acc[2][4];
    floatx4 vzero = {0.f, 0.f, 0.f, 0.f};
#pragma unroll
    for (int i = 0; i < 2; ++i)
#pragma unroll
        for (int j = 0; j < 4; ++j) acc[i][j] = vzero;

    for (int k0 = 0; k0 < Kdim; k0 += 64) {
#pragma unroll
        for (int j = 0; j < 4; ++j) {
            int f = j * 256 + tid, r = f >> 3, c = (f & 7) ^ (r & 7);
            async16(A + (size_t)(m0 + r) * Kdim + k0 + c * 8, lds + j * 4096 + w * 1024);
        }
#pragma unroll
        for (int j = 0; j < 2; ++j) {
            int f = j * 256 + tid, r = f >> 3, c = (f & 7) ^ (r & 7);
            async16(W + (size_t)(n0 + r) * Kdim + k0 + c * 8, lds + 16384 + j * 4096 + w * 1024);
        }
        __syncthreads();
        short8 af[2][2];
#pragma unroll
        for (int mt = 0; mt < 2; ++mt) {
            int ra = wm + mt * 16 + l15;
            const char* pa = lds + ra * 128;
#pragma unroll
            for (int ks = 0; ks < 2; ++ks)
                af[mt][ks] = *(const short8*)(pa + (((ks * 4 + quad) ^ (ra & 7)) << 4));
        }
#pragma unroll
        for (int ks = 0; ks < 2; ++ks)
#pragma unroll
            for (int nt = 0; nt < 4; ++nt) {
                int rb = nt * 16 + l15;
                short8 bf = *(const short8*)(lds + 16384 + rb * 128 + (((ks * 4 + quad) ^ (rb & 7)) << 4));
                acc[0][nt] = mfma16(af[0][ks], bf, acc[0][nt]);
                acc[1][nt] = mfma16(af[1][ks], bf, acc[1][nt]);
            }
        __syncthreads();
    }

    int mbase = m0 + wm;
    if (z <= 1) {
        float osc = (z == 0) ? QSCALE : 1.0f;
#pragma unroll
        for (int nt = 0; nt < 4; ++nt) {
            int col = n0 + nt * 16 + l15;
            float bv = bias[col];
            int p = (col & 63) >> 1;
#pragma unroll
            for (int mt = 0; mt < 2; ++mt) {
                floatx4 a = acc[mt][nt];
#pragma unroll
                for (int r = 0; r < 4; ++r) {
                    int row = mbase + mt * 16 + quad * 4 + r;
                    float v = a[r] + bv;
                    float ov = __shfl_xor(v, 1, 64);
                    float2 cs = rope[(row & (Tn - 1)) * 32 + p];
                    float res = (cs.x * v + ((lane & 1) ? cs.y * ov : -cs.y * ov)) * osc;
                    float pres = __shfl_xor(res, 1, 64);
                    if (!(lane & 1)) {
                        unsigned pk = (unsigned)f2bf(res) | ((unsigned)f2bf(pres) << 16);
                        *(unsigned*)(outp + (size_t)row * 1024 + col) = pk;
                    }
                }
            }
        }
    } else {
#pragma unroll
        for (int nt = 0; nt < 4; ++nt) {
            int col = n0 + nt * 16 + l15;
            float bv = bias[col];
#pragma unroll
            for (int mt = 0; mt < 2; ++mt) {
                floatx4 a = acc[mt][nt];
                int row0 = mbase + mt * 16 + quad * 4;
                int bb = row0 >> 11, t0 = row0 & (Tn - 1);
                u64 pk = (u64)f2bf(a[0] + bv) | ((u64)f2bf(a[1] + bv) << 16)
                       | ((u64)f2bf(a[2] + bv) << 32) | ((u64)f2bf(a[3] + bv) << 48);
                *(u64*)(outp + (size_t)(bb * 1024 + col) * Tn + t0) = pk;
            }
        }
    }
}

// ---------------- O-projection GEMM: out = Y(M,K) @ Wo(N,K)^T, f32 out, 64x64 tile ----------------
__global__ __launch_bounds__(256, 6) void gemm_o_k(
    const u16* __restrict__ A, const u16* __restrict__ W, float* __restrict__ out)
{
    __shared__ __align__(16) char lds[16384];
    int tid = threadIdx.x;
    int w = tid >> 6, lane = tid & 63, quad = lane >> 4, l15 = lane & 15;
    int m0 = blockIdx.y * 64, n0 = blockIdx.x * 64;
    int wm = (w >> 1) * 32, wn = (w & 1) * 32;

    floatx4 acc[2][2];
    floatx4 vzero = {0.f, 0.f, 0.f, 0.f};
#pragma unroll
    for (int i = 0; i < 2; ++i)
#pragma unroll
        for (int j = 0; j < 2; ++j) acc[i][j] = vzero;

    for (int k0 = 0; k0 < Kdim; k0 += 64) {
#pragma unroll
        for (int j = 0; j < 2; ++j) {
            int f = j * 256 + tid, r = f >> 3, c = (f & 7) ^ (r & 7);
            async16(A + (size_t)(m0 + r) * Kdim + k0 + c * 8, lds + j * 4096 + w * 1024);
            async16(W + (size_t)(n0 + r) * Kdim + k0 + c * 8, lds + 8192 + j * 4096 + w * 1024);
        }
        __syncthreads();
        short8 af[2][2];
#pragma unroll
        for (int mt = 0; mt < 2; ++mt) {
            int ra = wm + mt * 16 + l15;
            const char* pa = lds + ra * 128;
#pragma unroll
            for (int ks = 0; ks < 2; ++ks)
                af[mt][ks] = *(const short8*)(pa + (((ks * 4 + quad) ^ (ra & 7)) << 4));
        }
#pragma unroll
        for (int ks = 0; ks < 2; ++ks)
#pragma unroll
            for (int nt = 0; nt < 2; ++nt) {
                int rb = wn + nt * 16 + l15;
                short8 bf = *(const short8*)(lds + 8192 + rb * 128 + (((ks * 4 + quad) ^ (rb & 7)) << 4));
                acc[0][nt] = mfma16(af[0][ks], bf, acc[0][nt]);
                acc[1][nt] = mfma16(af[1][ks], bf, acc[1][nt]);
            }
        __syncthreads();
    }

#pragma unroll
    for (int nt = 0; nt < 2; ++nt) {
        int col = n0 + wn + nt * 16 + l15;
#pragma unroll
        for (int mt = 0; mt < 2; ++mt) {
            floatx4 a = acc[mt][nt];
#pragma unroll
            for (int r = 0; r < 4; ++r) {
                int row = m0 + wm + mt * 16 + quad * 4 + r;
                out[(size_t)row * 1024 + col] = a[r];
            }
        }
    }
}

// ---------------- Vmean (for degenerate fully-masked rows) ----------------
__global__ __launch_bounds__(64) void vmean_k(const u16* __restrict__ Vt, float* __restrict__ vmean) {
    int row = blockIdx.x;
    int lane = threadIdx.x;
    const u16* p = Vt + (size_t)row * Tn;
    float s = 0.f;
    for (int i = lane * 8; i < Tn; i += 512) {
        short8 v = *(const short8*)(p + i);
#pragma unroll
        for (int j = 0; j < 8; ++j) s += bf2f((u16)v[j]);
    }
#pragma unroll
    for (int off = 1; off < 64; off <<= 1) s += __shfl_xor(s, off, 64);
    if (lane == 0) vmean[row] = s * (1.f / 2048.f);
}

// ---------------- Flash attention v5: 2x2 wave split (q-half x key-half) ----------------
// R5 structure (1024 blocks x 256 thr, XCD cluster, dbuf async16 staging, 1 barrier/tile),
// but wave (qh,kh) computes S(32q x 32k) and a key-half PARTIAL O(32q x 64d): per-wave LDS
// frag reads drop 18 -> 10 b128 per tile. Fixed-max softmax => key-half partials are
// additive; one end-of-block LDS reduction merges them.
__global__ __launch_bounds__(256, 4) void flash_k(
    const u16* __restrict__ Qb, const u16* __restrict__ Kb, const u16* __restrict__ Vt,
    const int* __restrict__ masks, const float* __restrict__ vmean, u16* __restrict__ Yb)
{
    int bid = blockIdx.x;
    int bh = (bid & 7) * 4 + ((bid >> 3) & 3);   // XCD-clustered: 4 heads per XCD (bid%8)
    int qt = 31 - (bid >> 5);                    // big q-tiles dispatched first
    int b = bh >> 4, h = bh & 15;
    int tid = threadIdx.x, w = tid >> 6, lane = tid & 63, quad = lane >> 4, l15 = lane & 15;
    int kh = w & 1, qh = w >> 1;                 // wave = (q-half, key-half)
    int sc = (lane & 7) ^ (lane >> 3);           // staging chunk: LDS slot = chunk ^ (row&7)

    __shared__ __align__(16) u16 ldsK[2][64 * 64];   // row=key, 8x16B slots, swizzled (16KB)
    __shared__ __align__(16) u16 ldsV[2][64 * 64];   // row=d,   8x16B slots, swizzled (16KB)
    __shared__ __align__(16) u16 ldsP[4][32 * 32];   // per wave: 32 q-rows x 64B (2KB), swizzled

    int ktiles = qt + 1;
    // mask ballots in registers: lane j holds ballot of key-tile j
    unsigned blo = 0, bhi = 0;
    for (int j = 0; j < ktiles; ++j) {
        u64 mk = __ballot(masks[b * Tn + j * 64 + lane] != 0);
        if (lane == j) { blo = (unsigned)mk; bhi = (unsigned)(mk >> 32); }
    }

    auto stage = [&](int bb, int k0) {
#pragma unroll
        for (int j = 0; j < 2; ++j) {
            int row = j * 32 + w * 8 + (lane >> 3);
            const u16* gk = Kb + (size_t)(b * Tn + k0 + row) * 1024 + h * 64 + sc * 8;
            async16(gk, (char*)&ldsK[bb][0] + (j * 32 + w * 8) * 128);
            const u16* gv = Vt + (size_t)(b * 1024 + h * 64 + row) * Tn + k0 + sc * 8;
            async16(gv, (char*)&ldsV[bb][0] + (j * 32 + w * 8) * 128);
        }
    };

    int q0 = qt * 64 + qh * 32;
    short8 qf[2][2];
#pragma unroll
    for (int m2 = 0; m2 < 2; ++m2) {
        const u16* qp = Qb + (size_t)(b * Tn + q0 + m2 * 16 + l15) * 1024 + h * 64 + quad * 8;
        qf[m2][0] = *(const short8*)qp;
        qf[m2][1] = *(const short8*)(qp + 32);
    }

    floatx4 o[2][4];
    float lsum[2][4];
#pragma unroll
    for (int m2 = 0; m2 < 2; ++m2)
#pragma unroll
        for (int i = 0; i < 4; ++i) { o[m2][i] = (floatx4){0.f, 0.f, 0.f, 0.f}; lsum[m2][i] = 0.f; }

    char* pb = (char*)&ldsP[w][0];

    stage(0, 0);
    for (int kt = 0; kt < ktiles; ++kt) {
        int k0 = kt * 64;
        int bb = kt & 1;
        __syncthreads();   // tile kt staged; all waves done with other buffer

        // K frags: this wave's key-half (keys kh*32 + n2*16 + l15), d = ks*32 + quad*8
        short8 kf[2][2], vf[4];
#pragma unroll
        for (int n2 = 0; n2 < 2; ++n2) {
            int key = kh * 32 + n2 * 16 + l15;
            const char* kbase = (const char*)&ldsK[bb][0] + key * 128;
#pragma unroll
            for (int ks = 0; ks < 2; ++ks)
                kf[n2][ks] = *(const short8*)(kbase + (((ks * 4 + quad) ^ (key & 7)) << 4));
        }
        // V frags: rows d = nb*16 + l15, keys kh*32 + quad*8 .. +7
#pragma unroll
        for (int nb = 0; nb < 4; ++nb) {
            int row = nb * 16 + l15;
            vf[nb] = *(const short8*)((const char*)&ldsV[bb][0] + row * 128 +
                                      (((kh * 4 + quad) ^ (row & 7)) << 4));
        }
        if (kt + 1 < ktiles) stage(bb ^ 1, k0 + 64);   // prefetch flies during compute

        // mask + fixed-max folded into accumulator init
        unsigned mlo = __shfl(blo, kt, 64), mhi = __shfl(bhi, kt, 64);
        unsigned wmsk = kh ? mhi : mlo;
        floatx4 s[2][2];
#pragma unroll
        for (int n2 = 0; n2 < 2; ++n2) {
            float mi = ((wmsk >> (n2 * 16 + l15)) & 1) ? -1.0e10f : -FIXEDMAX;
            floatx4 ci = (floatx4){mi, mi, mi, mi};
            s[0][n2] = ci; s[1][n2] = ci;
        }
#pragma unroll
        for (int ks = 0; ks < 2; ++ks)
#pragma unroll
            for (int m2 = 0; m2 < 2; ++m2)
#pragma unroll
                for (int n2 = 0; n2 < 2; ++n2)
                    s[m2][n2] = mfma16(qf[m2][ks], kf[n2][ks], s[m2][n2]);

        bool diag = (kt == ktiles - 1);
#pragma unroll
        for (int m2 = 0; m2 < 2; ++m2) {
#pragma unroll
            for (int r = 0; r < 4; ++r) {
                int prow = m2 * 16 + quad * 4 + r;
                int lim = q0 + prow - k0 - kh * 32;   // key offsets > lim are causal-masked
                float ps = 0.f;
#pragma unroll
                for (int n2 = 0; n2 < 2; ++n2) {
                    float v = s[m2][n2][r];
                    if (diag && (n2 * 16 + l15 > lim)) v = -1.0e10f;
                    float p = __builtin_amdgcn_exp2f(v);
                    ps += p;
                    unsigned u = __float_as_uint(p) + 0x8000u;   // round-half-up bf16
                    // P strip: row=prow (64B rows), chunk = (n2*16+l15)>>3, slot = chunk^(prow&3)
                    *(u16*)(pb + prow * 64 + (((n2 * 2 + (l15 >> 3)) ^ (prow & 3)) << 4)
                            + (l15 & 7) * 2) = (u16)(u >> 16);
                }
                lsum[m2][r] += ps;
            }
        }
        __asm__ volatile("s_waitcnt lgkmcnt(0)" ::: "memory");   // wave-local P roundtrip
        short8 pf[2];
#pragma unroll
        for (int m2 = 0; m2 < 2; ++m2) {
            int prow = m2 * 16 + l15;
            pf[m2] = *(const short8*)(pb + prow * 64 + ((quad ^ (prow & 3)) << 4));
        }
#pragma unroll
        for (int m2 = 0; m2 < 2; ++m2)
#pragma unroll
            for (int nb = 0; nb < 4; ++nb)
                o[m2][nb] = mfma16(pf[m2], vf[nb], o[m2][nb]);
    }

    // ---- merge key-half partials (additive under fixed-max) ----
    __syncthreads();                              // all frag reads done; K/V LDS now dead
    float* red = (float*)&ldsK[0][0];             // [qh][idx 0..31][lane] f32 = 16KB
    float* lsr = (float*)&ldsV[0][0];             // [qh][idx 0..7][lane]  f32 = 4KB
    if (kh == 1) {
#pragma unroll
        for (int m2 = 0; m2 < 2; ++m2)
#pragma unroll
            for (int nb = 0; nb < 4; ++nb)
#pragma unroll
                for (int r = 0; r < 4; ++r)
                    red[qh * 2048 + (m2 * 16 + nb * 4 + r) * 64 + lane] = o[m2][nb][r];
#pragma unroll
        for (int m2 = 0; m2 < 2; ++m2)
#pragma unroll
            for (int r = 0; r < 4; ++r)
                lsr[qh * 512 + (m2 * 4 + r) * 64 + lane] = lsum[m2][r];
    }
    __syncthreads();
    if (kh == 0) {
#pragma unroll
        for (int m2 = 0; m2 < 2; ++m2)
#pragma unroll
            for (int nb = 0; nb < 4; ++nb)
#pragma unroll
                for (int r = 0; r < 4; ++r)
                    o[m2][nb][r] += red[qh * 2048 + (m2 * 16 + nb * 4 + r) * 64 + lane];
#pragma unroll
        for (int m2 = 0; m2 < 2; ++m2)
#pragma unroll
            for (int r = 0; r < 4; ++r) {
                float l = lsum[m2][r] + lsr[qh * 512 + (m2 * 4 + r) * 64 + lane];
#pragma unroll
                for (int off = 1; off < 16; off <<= 1) l += __shfl_xor(l, off, 64);
                int qq = q0 + m2 * 16 + quad * 4 + r;
                bool degen = (l == 0.f);   // fully-masked row -> uniform attn over ALL keys
                float linv = 1.0f / l;
#pragma unroll
                for (int nb = 0; nb < 4; ++nb) {
                    int d = nb * 16 + l15;
                    float val = degen ? vmean[b * 1024 + h * 64 + d] : o[m2][nb][r] * linv;
                    float pv = __shfl_xor(val, 1, 64);
                    if (!(lane & 1)) {
                        unsigned pk = (unsigned)f2bf(val) | ((unsigned)f2bf(pv) << 16);
                        *(unsigned*)(Yb + (size_t)(b * Tn + qq) * 1024 + h * 64 + d) = pk;
                    }
                }
            }
    }
}

extern "C" void kernel_launch(void* const* d_in, const int* in_sizes, int n_in,
                              void* d_out, int out_size, void* d_ws, size_t ws_size,
                              hipStream_t stream) {
    const float* x  = (const float*)d_in[0];
    const int* masks = (const int*)d_in[1];
    const float* Wq = (const float*)d_in[2];
    const float* bq = (const float*)d_in[3];
    const float* Wk = (const float*)d_in[4];
    const float* bk = (const float*)d_in[5];
    const float* Wv = (const float*)d_in[6];
    const float* bv = (const float*)d_in[7];
    const float* Wo = (const float*)d_in[8];
    const float2* rope = (const float2*)d_in[9];
    float* out = (float*)d_out;

    char* ws = (char*)d_ws;
    u16* xb   = (u16*)(ws);
    u16* Wqb  = (u16*)(ws + (8  << 20));
    u16* Wkb  = (u16*)(ws + (10 << 20));
    u16* Wvb  = (u16*)(ws + (12 << 20));
    u16* Wob  = (u16*)(ws + (14 << 20));
    u16* Qb   = (u16*)(ws + (16 << 20));
    u16* Kb2  = (u16*)(ws + (24 << 20));
    u16* Vt   = (u16*)(ws + (32 << 20));
    u16* Yb   = (u16*)(ws + (40 << 20));
    float* vm = (float*)(ws + (48 << 20));

    // fused f32 -> bf16 (x, Wq, Wk, Wv, Wo -> contiguous ws region)
    cvt_all_k<<<8192, 256, 0, stream>>>(x, Wq, Wk, Wv, Wo, xb);

    // fused QKV projection (+bias, rope on Q/K with QSCALE on Q, V transposed)
    gemm_qkv_k<<<dim3(16, 32, 3), 256, 0, stream>>>(xb, Wqb, Wkb, Wvb, bq, bk, bv,
                                                    Qb, Kb2, Vt, rope);
    // mean of V per (b,h,d) for degenerate fully-masked rows
    vmean_k<<<2048, 64, 0, stream>>>(Vt, vm);
    // flash attention (2x2 wave split, key-half partials)
    flash_k<<<1024, 256, 0, stream>>>(Qb, Kb2, Vt, masks, vm, Yb);
    // output projection -> f32 d_out
    gemm_o_k<<<dim3(16, 64), 256, 0, stream>>>(Yb, Wob, out);
}